// Round 6
// baseline (346.468 us; speedup 1.0000x reference)
//
#include <hip/hip_runtime.h>
#include <hip/hip_bf16.h>
#include <stdint.h>

typedef unsigned short u16;
typedef unsigned int u32;

#define T_TOK 8192
#define DIN   4096
#define DOUT  4096
#define NL    16
#define NR    16
#define KX    4096              // x part of extended-K
#define K2    4416              // 4096 + 256 (Z) + 64 (bias/onehot/pad) = 69*64
#define NKT   69                // K-tiles of 64
#define GITERS 34               // main-loop iterations (2 K-tiles each); K-tile 68 in tail

typedef __attribute__((ext_vector_type(8))) __bf16 bf16x8;
typedef __attribute__((ext_vector_type(4))) float  f32x4;

__device__ __forceinline__ u32 bf16rne(float f) {
    u32 x = __float_as_uint(f);
    return (x + 0x7FFFu + ((x >> 16) & 1u)) >> 16;
}
__device__ __forceinline__ u32 pack2(float a, float b) {
    return bf16rne(a) | (bf16rne(b) << 16);
}

// ---------------- pack: x -> A' cols 0..4095, W -> B' cols 0..4095 ----------------
__global__ void pack_mats(const float* __restrict__ x, const float* __restrict__ W,
                          u16* __restrict__ Abf, u16* __restrict__ Bbf) {
    const int total = (T_TOK + DOUT) * (DIN / 8);
    for (int i = blockIdx.x * blockDim.x + threadIdx.x; i < total;
         i += gridDim.x * blockDim.x) {
        int row = i >> 9;
        int c8  = (i & 511) << 3;
        const float* src;
        u16* dst;
        if (row < T_TOK) { src = x + (size_t)row * DIN; dst = Abf + (size_t)row * K2; }
        else { src = W + (size_t)(row - T_TOK) * DIN; dst = Bbf + (size_t)(row - T_TOK) * K2; }
        const float4* s = (const float4*)(src + c8);
        float4 f0 = s[0], f1 = s[1];
        uint4 u;
        u.x = pack2(f0.x, f0.y); u.y = pack2(f0.z, f0.w);
        u.z = pack2(f1.x, f1.y); u.w = pack2(f1.z, f1.w);
        *(uint4*)(dst + c8) = u;
    }
}

// ---------------- pack_small: B' extra cols + lora_a -> bf16 ----------------
#define NBEX (DOUT * 320)
__global__ void pack_small(const float* __restrict__ lora_b,
                           const float* __restrict__ base_bias,
                           const float* __restrict__ bias_st,
                           const float* __restrict__ la,
                           u16* __restrict__ Bbf, u16* __restrict__ Aabf) {
    const int total = NBEX + NL * NR * DIN / 8;
    for (int i = blockIdx.x * blockDim.x + threadIdx.x; i < total;
         i += gridDim.x * blockDim.x) {
        if (i < NBEX) {
            int o = i / 320;
            int j = i - o * 320;
            float v = 0.f;
            if (j < 256) {
                int l = j >> 4, r = j & 15;
                v = lora_b[((size_t)l * DOUT + o) * NR + r];
            } else if (j == 256) {
                v = base_bias[o];
            } else if (j < 273) {
                v = bias_st[(size_t)(j - 257) * DOUT + o];
            }
            Bbf[(size_t)o * K2 + KX + j] = (u16)bf16rne(v);
        } else {
            int c8 = (i - NBEX) << 3;
            const float4* s = (const float4*)(la + c8);
            float4 f0 = s[0], f1 = s[1];
            uint4 u;
            u.x = pack2(f0.x, f0.y); u.y = pack2(f0.z, f0.w);
            u.z = pack2(f1.x, f1.y); u.w = pack2(f1.z, f1.w);
            *(uint4*)(Aabf + c8) = u;
        }
    }
}

// ---------------- zfill: Zfull = x_bf16 @ lora_a^T via MFMA, masked write ----------------
__global__ __launch_bounds__(512) void zfill_kernel(const u16* __restrict__ Axr,
                                                    const u16* __restrict__ La,
                                                    const int* __restrict__ idx,
                                                    u16* __restrict__ Abf) {
    __shared__ u16 sX[2][64 * 64];
    __shared__ u16 sL[2][128 * 64];
    const int tid  = threadIdx.x;
    const int lane = tid & 63, wid = tid >> 6;
    const int wr = wid >> 2, wc = wid & 3;
    const int lrow = lane & 15;
    const int klo  = (lane >> 4) << 4;
    const int sxr  = (lrow & 7) << 4;
    const int kxb[2] = { klo ^ sxr, (64 + klo) ^ sxr };

    const int bt = blockIdx.x >> 1;
    const int nh = blockIdx.x & 1;

    const int r0 = tid >> 3;
    const int c4 = (tid & 7) ^ (r0 & 7);
    const u16* pX = Axr + (size_t)(bt * 64 + r0) * K2 + c4 * 8;
    const u16* pL = La + (size_t)(nh * 128 + r0) * DIN + c4 * 8;
    const u16* pL2 = La + (size_t)(nh * 128 + 64 + r0) * DIN + c4 * 8;

    f32x4 acc[2][2];
#pragma unroll
    for (int m = 0; m < 2; ++m)
#pragma unroll
        for (int n = 0; n < 2; ++n) { f32x4 z = {0.f,0.f,0.f,0.f}; acc[m][n] = z; }

#define STAGEZ(buf, kt)                                                                \
  do {                                                                                 \
    __builtin_amdgcn_global_load_lds(                                                  \
      (const __attribute__((address_space(1))) u32*)(pX + (size_t)(kt) * 64),          \
      (__attribute__((address_space(3))) u32*)(&sX[buf][tid * 8]), 16, 0, 0);          \
    __builtin_amdgcn_global_load_lds(                                                  \
      (const __attribute__((address_space(1))) u32*)(pL + (size_t)(kt) * 64),          \
      (__attribute__((address_space(3))) u32*)(&sL[buf][tid * 8]), 16, 0, 0);          \
    __builtin_amdgcn_global_load_lds(                                                  \
      (const __attribute__((address_space(1))) u32*)(pL2 + (size_t)(kt) * 64),         \
      (__attribute__((address_space(3))) u32*)(&sL[buf][4096 + tid * 8]), 16, 0, 0);   \
  } while (0)

    STAGEZ(0, 0);
    for (int kt = 0; kt < 64; ++kt) {
        const int cur = kt & 1;
        if (kt < 63) {
            STAGEZ(cur ^ 1, kt + 1);
            asm volatile("s_waitcnt vmcnt(3)" ::: "memory");
        } else {
            asm volatile("s_waitcnt vmcnt(0)" ::: "memory");
        }
        __builtin_amdgcn_sched_barrier(0);
        __builtin_amdgcn_s_barrier();
        __builtin_amdgcn_sched_barrier(0);
        const char* sx = (const char*)sX[cur];
        const char* sl = (const char*)sL[cur];
        bf16x8 a[2][2], b[2][2];
#pragma unroll
        for (int m = 0; m < 2; ++m)
#pragma unroll
            for (int kk = 0; kk < 2; ++kk)
                a[m][kk] = *(const bf16x8*)(sx + (wr * 32 + m * 16 + lrow) * 128 + kxb[kk]);
#pragma unroll
        for (int n = 0; n < 2; ++n)
#pragma unroll
            for (int kk = 0; kk < 2; ++kk)
                b[n][kk] = *(const bf16x8*)(sl + (wc * 32 + n * 16 + lrow) * 128 + kxb[kk]);
#pragma unroll
        for (int m = 0; m < 2; ++m)
#pragma unroll
            for (int n = 0; n < 2; ++n)
#pragma unroll
                for (int kk = 0; kk < 2; ++kk)
                    acc[m][n] = __builtin_amdgcn_mfma_f32_16x16x32_bf16(
                        a[m][kk], b[n][kk], acc[m][n], 0, 0, 0);
        __builtin_amdgcn_sched_barrier(0);
        __builtin_amdgcn_s_barrier();
        __builtin_amdgcn_sched_barrier(0);
    }

#pragma unroll
    for (int m = 0; m < 2; ++m) {
#pragma unroll
        for (int rg = 0; rg < 4; ++rg) {
            int tl = wr * 32 + m * 16 + ((lane >> 4) << 2) + rg;
            int t  = bt * 64 + tl;
            int l  = idx[t];
#pragma unroll
            for (int n = 0; n < 2; ++n) {
                int col = nh * 128 + wc * 32 + n * 16 + (lane & 15);
                u16 v = ((col >> 4) == l) ? (u16)bf16rne(acc[m][n][rg]) : (u16)0;
                Abf[(size_t)t * K2 + KX + col] = v;
            }
        }
    }
    if (nh == 0) {
        int tl = tid >> 3, c8 = (tid & 7) * 8;
        int t = bt * 64 + tl;
        int l = idx[t];
        u32 w[4];
#pragma unroll
        for (int q = 0; q < 4; ++q) {
            int c0 = KX + 256 + c8 + 2 * q;
            u32 v0 = (c0 == 4352 || (l >= 0 && c0 == 4353 + l)) ? 0x3F80u : 0u;
            int c1 = c0 + 1;
            u32 v1 = (c1 == 4352 || (l >= 0 && c1 == 4353 + l)) ? 0x3F80u : 0u;
            w[q] = v0 | (v1 << 16);
        }
        *(uint4*)(Abf + (size_t)t * K2 + KX + 256 + c8) = *(uint4*)w;
    }
}

// ---------------- main GEMM: 256x256 tile, 4-phase/iter, 16x16x32 MFMA, 1 barrier/phase --
// 8 waves (2M x 4N), BK=64, 128 KiB LDS. Derived 4-phase schedule (32 MFMA +
// 16/8 ds_read per phase): stage slots ph1:{O.A1,O.B1->b1} ph2:{E'.A0,B0->b0}
// ph3:{E'.A1,B1->b0} ph4:{O'.A0,B0->b1}; every seg staged >=1 phase after its
// last read; vmcnt(4) guards at ph2/ph4 (ledger: 12 outstanding, oldest 8 =
// next-needed tile). Reads are consumed in-phase (lgkm drained before use), so
// the single end-of-phase barrier implies read completion.

#define SBAR() __builtin_amdgcn_sched_barrier(0)
#define HWBAR() __builtin_amdgcn_s_barrier()
#define PHASE_BAR() do { SBAR(); HWBAR(); SBAR(); } while (0)
#define VMCNT4() asm volatile("s_waitcnt vmcnt(4)" ::: "memory")
#define VMCNT0() asm volatile("s_waitcnt vmcnt(0)" ::: "memory")

#define STAGE(ptr, h, buf, seg, kt)                                                   \
  do { if ((kt) < NKT) {                                                              \
    __builtin_amdgcn_global_load_lds(                                                 \
      (const __attribute__((address_space(1))) u32*)((ptr) + (size_t)((h)*128 + 0)*K2 + (size_t)(kt)*64),  \
      (__attribute__((address_space(3))) u32*)(lds16 + ((((buf)*4+(seg))<<13) + tid*8)), 16, 0, 0);        \
    __builtin_amdgcn_global_load_lds(                                                 \
      (const __attribute__((address_space(1))) u32*)((ptr) + (size_t)((h)*128 + 64)*K2 + (size_t)(kt)*64), \
      (__attribute__((address_space(3))) u32*)(lds16 + ((((buf)*4+(seg))<<13) + tid*8 + 4096)), 16, 0, 0); \
  } } while (0)

// read one m-half of A (4 frags x 2 k-chunks = 8 ds_read_b128)
#define RD_AH(buf, mh, aa)                                                            \
  { _Pragma("unroll") for (int mm = 0; mm < 4; ++mm)                                  \
    _Pragma("unroll") for (int kk = 0; kk < 2; ++kk)                                  \
      aa[mm][kk] = *(const bf16x8*)(smem + (((buf)*4 + wr) << 14) + lrow*128          \
          + (mh)*8192 + mm*2048 + kxb[kk]); }

// read one n-half of B (2 frags x 2 k-chunks = 4 ds_read_b128)
#define RD_BH(buf, nh, bf)                                                            \
  { _Pragma("unroll") for (int nn = 0; nn < 2; ++nn)                                  \
    _Pragma("unroll") for (int kk = 0; kk < 2; ++kk)                                  \
      bf[nn][kk] = *(const bf16x8*)(smem + (((buf)*4 + 2 + (wc>>1)) << 14)            \
          + ((wc&1)*64 + lrow)*128 + ((nh)*2+nn)*2048 + kxb[kk]); }

#define MMQ(mh, nh, aa, bf)                                                           \
  { __builtin_amdgcn_s_setprio(1);                                                    \
    _Pragma("unroll") for (int mm = 0; mm < 4; ++mm)                                  \
    _Pragma("unroll") for (int nn = 0; nn < 2; ++nn)                                  \
    _Pragma("unroll") for (int kk = 0; kk < 2; ++kk)                                  \
      acc[(mh)*4+mm][(nh)*2+nn] = __builtin_amdgcn_mfma_f32_16x16x32_bf16(            \
          aa[mm][kk], bf[nn][kk], acc[(mh)*4+mm][(nh)*2+nn], 0, 0, 0);                \
    __builtin_amdgcn_s_setprio(0); }

__global__ __launch_bounds__(512, 2) void gemm_kernel(const u16* __restrict__ A,
                                                      const u16* __restrict__ B,
                                                      float* __restrict__ C) {
    __shared__ u16 lds16[65536];                 // 128 KiB
    const char* smem = (const char*)lds16;

    const int tid  = threadIdx.x;
    const int lane = tid & 63, wid = tid >> 6;
    const int wr = wid >> 2, wc = wid & 3;       // 2M x 4N wave grid
    const int lrow = lane & 15;
    const int klo  = (lane >> 4) << 4;
    const int sx   = (lrow & 7) << 4;
    const int kxb[2] = { klo ^ sx, (64 + klo) ^ sx };

    // XCD-aware swizzle: 512 blocks, 512 % 8 == 0 -> bijective
    const int wg  = blockIdx.x;
    const int swz = (wg & 7) * 64 + (wg >> 3);
    const int bm = swz >> 4;                     // 32 row-tiles
    const int bn = swz & 15;                     // 16 col-tiles

    const int r0  = tid >> 3;
    const int sc4 = (tid & 7) ^ (r0 & 7);
    const u16* pA = A + (size_t)(bm * 256 + r0) * K2 + sc4 * 8;
    const u16* pB = B + (size_t)(bn * 256 + r0) * K2 + sc4 * 8;

    f32x4 acc[8][4];
#pragma unroll
    for (int m = 0; m < 8; ++m)
#pragma unroll
        for (int n = 0; n < 4; ++n) { f32x4 z = {0.f,0.f,0.f,0.f}; acc[m][n] = z; }
    bf16x8 a0[4][2], a1[4][2], bA[2][2], bB[2][2];

    // prologue: K0 all 4 segs (b0) + K1 A0,B0 (b1 segs 0,2); K1 A1,B1 at ph1
    STAGE(pA, 0, 0, 0, 0); STAGE(pA, 1, 0, 1, 0);
    STAGE(pB, 0, 0, 2, 0); STAGE(pB, 1, 0, 3, 0);
    STAGE(pA, 0, 1, 0, 1); STAGE(pB, 0, 1, 2, 1);
    VMCNT4();                                    // 12 out -> K0's 8 landed
    PHASE_BAR();

    for (int i = 0; i < GITERS; ++i) {
        const int kO = 2 * i + 1, kE2 = 2 * i + 2, kO2 = 2 * i + 3;
        // ph1: E=2i (mh0 x both nh); stage O.A1->b1.s1 (s1 read prev ph4),
        //      O.B1->b1.s3 (B segs read prev ph3)
        RD_AH(0, 0, a0); RD_BH(0, 0, bA); RD_BH(0, 1, bB);
        STAGE(pA, 1, 1, 1, kO); STAGE(pB, 1, 1, 3, kO);
        MMQ(0, 0, a0, bA); MMQ(0, 1, a0, bB);
        PHASE_BAR();
        // ph2: E (mh1 x both nh); stage E'.A0->b0.s0, E'.B0->b0.s2 (read ph1);
        //      guard: O=2i+1 landed (issued prev-ph4 + ph1; oldest 8 of 12)
        RD_AH(0, 1, a1);
        STAGE(pA, 0, 0, 0, kE2); STAGE(pB, 0, 0, 2, kE2);
        MMQ(1, 0, a1, bA); MMQ(1, 1, a1, bB);
        VMCNT4();
        PHASE_BAR();
        // ph3: O (mh0 x both nh); stage E'.A1->b0.s1 (read ph2), E'.B1->b0.s3 (read ph1)
        RD_AH(1, 0, a0); RD_BH(1, 0, bA); RD_BH(1, 1, bB);
        STAGE(pA, 1, 0, 1, kE2); STAGE(pB, 1, 0, 3, kE2);
        MMQ(0, 0, a0, bA); MMQ(0, 1, a0, bB);
        PHASE_BAR();
        // ph4: O (mh1 x both nh); stage O'.A0->b1.s0, O'.B0->b1.s2 (read ph3);
        //      guard: E'=2i+2 landed (issued ph2+ph3; oldest 8 of 12)
        RD_AH(1, 1, a1);
        STAGE(pA, 0, 1, 0, kO2); STAGE(pB, 0, 1, 2, kO2);
        MMQ(1, 0, a1, bA); MMQ(1, 1, a1, bB);
        VMCNT4();
        PHASE_BAR();
    }

    // tail: K-tile 68 (b0), staged during iter 33 ph2 (A0,B0) + ph3 (A1,B1)
    VMCNT0();
    PHASE_BAR();
    RD_AH(0, 0, a0); RD_AH(0, 1, a1); RD_BH(0, 0, bA); RD_BH(0, 1, bB);
    MMQ(0, 0, a0, bA); MMQ(1, 0, a1, bA); MMQ(0, 1, a0, bB); MMQ(1, 1, a1, bB);

    // epilogue: C/D layout col = lane&15, row = (lane>>4)*4 + reg
    const int crow0 = bm * 256 + wr * 128 + ((lane >> 4) << 2);
    const int ccol0 = bn * 256 + wc * 64 + (lane & 15);
#pragma unroll
    for (int m = 0; m < 8; ++m)
#pragma unroll
        for (int n = 0; n < 4; ++n)
#pragma unroll
            for (int rg = 0; rg < 4; ++rg)
                C[(size_t)(crow0 + m * 16 + rg) * DOUT + ccol0 + n * 16] = acc[m][n][rg];
}

// ---------------- launch ----------------

extern "C" void kernel_launch(void* const* d_in, const int* in_sizes, int n_in,
                              void* d_out, int out_size, void* d_ws, size_t ws_size,
                              hipStream_t stream) {
    const float* x         = (const float*)d_in[0];
    const float* W         = (const float*)d_in[1];
    const float* base_bias = (const float*)d_in[2];
    const float* lora_a    = (const float*)d_in[3];
    const float* lora_b    = (const float*)d_in[4];
    const float* bias_st   = (const float*)d_in[5];
    const int*   indices   = (const int*)d_in[6];
    float* out = (float*)d_out;

    u16* Abf  = (u16*)d_ws;                         // [T_TOK][K2] bf16
    u16* Bbf  = Abf + (size_t)T_TOK * K2;           // [DOUT][K2] bf16
    u16* Aabf = Bbf + (size_t)DOUT * K2;            // [256][DIN] bf16 lora_a

    pack_mats<<<6144, 256, 0, stream>>>(x, W, Abf, Bbf);
    pack_small<<<1536, 256, 0, stream>>>(lora_b, base_bias, bias_st, lora_a, Bbf, Aabf);
    zfill_kernel<<<256, 512, 0, stream>>>(Abf, Aabf, indices, Abf);
    gemm_kernel<<<512, 512, 0, stream>>>(Abf, Bbf, out);
    (void)in_sizes; (void)n_in; (void)out_size; (void)ws_size;
}

// Round 7
// 336.840 us; speedup vs baseline: 1.0286x; 1.0286x over previous
//
#include <hip/hip_runtime.h>
#include <hip/hip_bf16.h>
#include <stdint.h>

typedef unsigned short u16;
typedef unsigned int u32;

#define T_TOK 8192
#define DIN   4096
#define DOUT  4096
#define NL    16
#define NR    16
#define KX    4096              // x part of extended-K
#define K2    4416              // 4096 + 256 (Z) + 64 (bias/onehot/pad) = 69*64
#define NKT   69                // K-tiles of 64
#define GITERS 34               // main-loop iterations (2 K-tiles each); K-tile 68 in tail

typedef __attribute__((ext_vector_type(8))) __bf16 bf16x8;
typedef __attribute__((ext_vector_type(4))) float  f32x4;

__device__ __forceinline__ u32 bf16rne(float f) {
    u32 x = __float_as_uint(f);
    return (x + 0x7FFFu + ((x >> 16) & 1u)) >> 16;
}
__device__ __forceinline__ u32 pack2(float a, float b) {
    return bf16rne(a) | (bf16rne(b) << 16);
}

// ---------------- pack: x -> A' cols 0..4095, W -> B' cols 0..4095 ----------------
__global__ void pack_mats(const float* __restrict__ x, const float* __restrict__ W,
                          u16* __restrict__ Abf, u16* __restrict__ Bbf) {
    const int total = (T_TOK + DOUT) * (DIN / 8);
    for (int i = blockIdx.x * blockDim.x + threadIdx.x; i < total;
         i += gridDim.x * blockDim.x) {
        int row = i >> 9;
        int c8  = (i & 511) << 3;
        const float* src;
        u16* dst;
        if (row < T_TOK) { src = x + (size_t)row * DIN; dst = Abf + (size_t)row * K2; }
        else { src = W + (size_t)(row - T_TOK) * DIN; dst = Bbf + (size_t)(row - T_TOK) * K2; }
        const float4* s = (const float4*)(src + c8);
        float4 f0 = s[0], f1 = s[1];
        uint4 u;
        u.x = pack2(f0.x, f0.y); u.y = pack2(f0.z, f0.w);
        u.z = pack2(f1.x, f1.y); u.w = pack2(f1.z, f1.w);
        *(uint4*)(dst + c8) = u;
    }
}

// ---------------- pack_small: B' extra cols + lora_a -> bf16 ----------------
#define NBEX (DOUT * 320)
__global__ void pack_small(const float* __restrict__ lora_b,
                           const float* __restrict__ base_bias,
                           const float* __restrict__ bias_st,
                           const float* __restrict__ la,
                           u16* __restrict__ Bbf, u16* __restrict__ Aabf) {
    const int total = NBEX + NL * NR * DIN / 8;
    for (int i = blockIdx.x * blockDim.x + threadIdx.x; i < total;
         i += gridDim.x * blockDim.x) {
        if (i < NBEX) {
            int o = i / 320;
            int j = i - o * 320;
            float v = 0.f;
            if (j < 256) {
                int l = j >> 4, r = j & 15;
                v = lora_b[((size_t)l * DOUT + o) * NR + r];
            } else if (j == 256) {
                v = base_bias[o];
            } else if (j < 273) {
                v = bias_st[(size_t)(j - 257) * DOUT + o];
            }
            Bbf[(size_t)o * K2 + KX + j] = (u16)bf16rne(v);
        } else {
            int c8 = (i - NBEX) << 3;
            const float4* s = (const float4*)(la + c8);
            float4 f0 = s[0], f1 = s[1];
            uint4 u;
            u.x = pack2(f0.x, f0.y); u.y = pack2(f0.z, f0.w);
            u.z = pack2(f1.x, f1.y); u.w = pack2(f1.z, f1.w);
            *(uint4*)(Aabf + c8) = u;
        }
    }
}

// ---------------- zfill: Zfull = x_bf16 @ lora_a^T via MFMA, masked write ----------------
__global__ __launch_bounds__(512) void zfill_kernel(const u16* __restrict__ Axr,
                                                    const u16* __restrict__ La,
                                                    const int* __restrict__ idx,
                                                    u16* __restrict__ Abf) {
    __shared__ u16 sX[2][64 * 64];
    __shared__ u16 sL[2][128 * 64];
    const int tid  = threadIdx.x;
    const int lane = tid & 63, wid = tid >> 6;
    const int wr = wid >> 2, wc = wid & 3;
    const int lrow = lane & 15;
    const int klo  = (lane >> 4) << 4;
    const int sxr  = (lrow & 7) << 4;
    const int kxb[2] = { klo ^ sxr, (64 + klo) ^ sxr };

    const int bt = blockIdx.x >> 1;
    const int nh = blockIdx.x & 1;

    const int r0 = tid >> 3;
    const int c4 = (tid & 7) ^ (r0 & 7);
    const u16* pX = Axr + (size_t)(bt * 64 + r0) * K2 + c4 * 8;
    const u16* pL = La + (size_t)(nh * 128 + r0) * DIN + c4 * 8;
    const u16* pL2 = La + (size_t)(nh * 128 + 64 + r0) * DIN + c4 * 8;

    f32x4 acc[2][2];
#pragma unroll
    for (int m = 0; m < 2; ++m)
#pragma unroll
        for (int n = 0; n < 2; ++n) { f32x4 z = {0.f,0.f,0.f,0.f}; acc[m][n] = z; }

#define STAGEZ(buf, kt)                                                                \
  do {                                                                                 \
    __builtin_amdgcn_global_load_lds(                                                  \
      (const __attribute__((address_space(1))) u32*)(pX + (size_t)(kt) * 64),          \
      (__attribute__((address_space(3))) u32*)(&sX[buf][tid * 8]), 16, 0, 0);          \
    __builtin_amdgcn_global_load_lds(                                                  \
      (const __attribute__((address_space(1))) u32*)(pL + (size_t)(kt) * 64),          \
      (__attribute__((address_space(3))) u32*)(&sL[buf][tid * 8]), 16, 0, 0);          \
    __builtin_amdgcn_global_load_lds(                                                  \
      (const __attribute__((address_space(1))) u32*)(pL2 + (size_t)(kt) * 64),         \
      (__attribute__((address_space(3))) u32*)(&sL[buf][4096 + tid * 8]), 16, 0, 0);   \
  } while (0)

    STAGEZ(0, 0);
    for (int kt = 0; kt < 64; ++kt) {
        const int cur = kt & 1;
        if (kt < 63) {
            STAGEZ(cur ^ 1, kt + 1);
            asm volatile("s_waitcnt vmcnt(3)" ::: "memory");
        } else {
            asm volatile("s_waitcnt vmcnt(0)" ::: "memory");
        }
        __builtin_amdgcn_sched_barrier(0);
        __builtin_amdgcn_s_barrier();
        __builtin_amdgcn_sched_barrier(0);
        const char* sx = (const char*)sX[cur];
        const char* sl = (const char*)sL[cur];
        bf16x8 a[2][2], b[2][2];
#pragma unroll
        for (int m = 0; m < 2; ++m)
#pragma unroll
            for (int kk = 0; kk < 2; ++kk)
                a[m][kk] = *(const bf16x8*)(sx + (wr * 32 + m * 16 + lrow) * 128 + kxb[kk]);
#pragma unroll
        for (int n = 0; n < 2; ++n)
#pragma unroll
            for (int kk = 0; kk < 2; ++kk)
                b[n][kk] = *(const bf16x8*)(sl + (wc * 32 + n * 16 + lrow) * 128 + kxb[kk]);
#pragma unroll
        for (int m = 0; m < 2; ++m)
#pragma unroll
            for (int n = 0; n < 2; ++n)
#pragma unroll
                for (int kk = 0; kk < 2; ++kk)
                    acc[m][n] = __builtin_amdgcn_mfma_f32_16x16x32_bf16(
                        a[m][kk], b[n][kk], acc[m][n], 0, 0, 0);
        __builtin_amdgcn_sched_barrier(0);
        __builtin_amdgcn_s_barrier();
        __builtin_amdgcn_sched_barrier(0);
    }

#pragma unroll
    for (int m = 0; m < 2; ++m) {
#pragma unroll
        for (int rg = 0; rg < 4; ++rg) {
            int tl = wr * 32 + m * 16 + ((lane >> 4) << 2) + rg;
            int t  = bt * 64 + tl;
            int l  = idx[t];
#pragma unroll
            for (int n = 0; n < 2; ++n) {
                int col = nh * 128 + wc * 32 + n * 16 + (lane & 15);
                u16 v = ((col >> 4) == l) ? (u16)bf16rne(acc[m][n][rg]) : (u16)0;
                Abf[(size_t)t * K2 + KX + col] = v;
            }
        }
    }
    if (nh == 0) {
        int tl = tid >> 3, c8 = (tid & 7) * 8;
        int t = bt * 64 + tl;
        int l = idx[t];
        u32 w[4];
#pragma unroll
        for (int q = 0; q < 4; ++q) {
            int c0 = KX + 256 + c8 + 2 * q;
            u32 v0 = (c0 == 4352 || (l >= 0 && c0 == 4353 + l)) ? 0x3F80u : 0u;
            int c1 = c0 + 1;
            u32 v1 = (c1 == 4352 || (l >= 0 && c1 == 4353 + l)) ? 0x3F80u : 0u;
            w[q] = v0 | (v1 << 16);
        }
        *(uint4*)(Abf + (size_t)t * K2 + KX + 256 + c8) = *(uint4*)w;
    }
}

// ---------------- main GEMM: 256x256, 4-phase RD-AHEAD pipeline, 16x16x32 MFMA --------
// 8 waves (2M x 4N), BK=64, 128 KiB LDS. Each phase: MMQ on regs loaded LAST
// phase -> [vmcnt guard] -> RD(next phase's frags) -> STAGE -> lgkmcnt(0) ->
// barrier. Stage slots: ph1 E'.B, ph2 E'.A, ph3 O'.B, ph4 O'.A (4 DMA/phase);
// guards vmcnt(4) mid-ph2 (b1 landed) / mid-ph4 (b0=E' landed); last iter ph4
// uses vmcnt(0) (ph3 stage skipped breaks the oldest-8 ledger). lgkmcnt(0)
// before each barrier because RD results now cross it.

#define SBAR() __builtin_amdgcn_sched_barrier(0)
#define HWBAR() __builtin_amdgcn_s_barrier()
#define PHASE_BAR() do { SBAR(); asm volatile("s_waitcnt lgkmcnt(0)" ::: "memory"); \
                         SBAR(); HWBAR(); SBAR(); } while (0)
#define VMCNT4() asm volatile("s_waitcnt vmcnt(4)" ::: "memory")
#define VMCNT0() asm volatile("s_waitcnt vmcnt(0)" ::: "memory")

#define STAGE(ptr, h, buf, seg, kt)                                                   \
  do { if ((kt) < NKT) {                                                              \
    __builtin_amdgcn_global_load_lds(                                                 \
      (const __attribute__((address_space(1))) u32*)((ptr) + (size_t)((h)*128 + 0)*K2 + (size_t)(kt)*64),  \
      (__attribute__((address_space(3))) u32*)(lds16 + ((((buf)*4+(seg))<<13) + tid*8)), 16, 0, 0);        \
    __builtin_amdgcn_global_load_lds(                                                 \
      (const __attribute__((address_space(1))) u32*)((ptr) + (size_t)((h)*128 + 64)*K2 + (size_t)(kt)*64), \
      (__attribute__((address_space(3))) u32*)(lds16 + ((((buf)*4+(seg))<<13) + tid*8 + 4096)), 16, 0, 0); \
  } } while (0)

// read one m-half of A (4 frags x 2 k-chunks = 8 ds_read_b128)
#define RD_AH(buf, mh, aa)                                                            \
  { _Pragma("unroll") for (int mm = 0; mm < 4; ++mm)                                  \
    _Pragma("unroll") for (int kk = 0; kk < 2; ++kk)                                  \
      aa[mm][kk] = *(const bf16x8*)(smem + (((buf)*4 + wr) << 14) + lrow*128          \
          + (mh)*8192 + mm*2048 + kxb[kk]); }

// read one n-half of B (2 frags x 2 k-chunks = 4 ds_read_b128)
#define RD_BH(buf, nh, bf)                                                            \
  { _Pragma("unroll") for (int nn = 0; nn < 2; ++nn)                                  \
    _Pragma("unroll") for (int kk = 0; kk < 2; ++kk)                                  \
      bf[nn][kk] = *(const bf16x8*)(smem + (((buf)*4 + 2 + (wc>>1)) << 14)            \
          + ((wc&1)*64 + lrow)*128 + ((nh)*2+nn)*2048 + kxb[kk]); }

#define MMQ(mh, nh, aa, bf)                                                           \
  { __builtin_amdgcn_s_setprio(1);                                                    \
    _Pragma("unroll") for (int mm = 0; mm < 4; ++mm)                                  \
    _Pragma("unroll") for (int nn = 0; nn < 2; ++nn)                                  \
    _Pragma("unroll") for (int kk = 0; kk < 2; ++kk)                                  \
      acc[(mh)*4+mm][(nh)*2+nn] = __builtin_amdgcn_mfma_f32_16x16x32_bf16(            \
          aa[mm][kk], bf[nn][kk], acc[(mh)*4+mm][(nh)*2+nn], 0, 0, 0);                \
    __builtin_amdgcn_s_setprio(0); }

__global__ __launch_bounds__(512, 2) void gemm_kernel(const u16* __restrict__ A,
                                                      const u16* __restrict__ B,
                                                      float* __restrict__ C) {
    __shared__ u16 lds16[65536];                 // 128 KiB
    const char* smem = (const char*)lds16;

    const int tid  = threadIdx.x;
    const int lane = tid & 63, wid = tid >> 6;
    const int wr = wid >> 2, wc = wid & 3;       // 2M x 4N wave grid
    const int lrow = lane & 15;
    const int klo  = (lane >> 4) << 4;
    const int sx   = (lrow & 7) << 4;
    const int kxb[2] = { klo ^ sx, (64 + klo) ^ sx };

    // XCD-aware swizzle: 512 blocks, 512 % 8 == 0 -> bijective
    const int wg  = blockIdx.x;
    const int swz = (wg & 7) * 64 + (wg >> 3);
    const int bm = swz >> 4;                     // 32 row-tiles
    const int bn = swz & 15;                     // 16 col-tiles

    const int r0  = tid >> 3;
    const int sc4 = (tid & 7) ^ (r0 & 7);
    const u16* pA = A + (size_t)(bm * 256 + r0) * K2 + sc4 * 8;
    const u16* pB = B + (size_t)(bn * 256 + r0) * K2 + sc4 * 8;

    f32x4 acc[8][4];
#pragma unroll
    for (int m = 0; m < 8; ++m)
#pragma unroll
        for (int n = 0; n < 4; ++n) { f32x4 z = {0.f,0.f,0.f,0.f}; acc[m][n] = z; }
    bf16x8 a0[4][2], a1[4][2], bA[2][2], bB[2][2];

    // prologue: K0 all segs (b0, 8 DMA) + K1.B (b1, 4 DMA); guard K0; preload
    // K0 mh0 frags; then K1.A (4 DMA) -> outstanding 8 = all of b1 (steady state)
    STAGE(pA, 0, 0, 0, 0); STAGE(pA, 1, 0, 1, 0);
    STAGE(pB, 0, 0, 2, 0); STAGE(pB, 1, 0, 3, 0);
    STAGE(pB, 0, 1, 2, 1); STAGE(pB, 1, 1, 3, 1);
    VMCNT4();                                    // 12 out -> K0's 8 landed
    PHASE_BAR();
    RD_AH(0, 0, a0); RD_BH(0, 0, bA); RD_BH(0, 1, bB);
    STAGE(pA, 0, 1, 0, 1); STAGE(pA, 1, 1, 1, 1);
    PHASE_BAR();

    for (int i = 0; i < GITERS; ++i) {
        const int kE2 = 2 * i + 2, kO2 = 2 * i + 3;
        // ph1: E mh0 (regs from prev ph4); RD E mh1; stage E'.B -> b0.s2/s3
        //      (b0.B last read prev ph4, drained at its barrier)
        MMQ(0, 0, a0, bA); MMQ(0, 1, a0, bB);
        RD_AH(0, 1, a1);
        STAGE(pB, 0, 0, 2, kE2); STAGE(pB, 1, 0, 3, kE2);
        PHASE_BAR();
        // ph2: E mh1; guard b1=O landed (ledger 12: oldest 8 = O); RD O mh0;
        //      stage E'.A -> b0.s0/s1 (b0.A last read ph1)
        MMQ(1, 0, a1, bA); MMQ(1, 1, a1, bB);
        VMCNT4();
        RD_AH(1, 0, a0); RD_BH(1, 0, bA); RD_BH(1, 1, bB);
        STAGE(pA, 0, 0, 0, kE2); STAGE(pA, 1, 0, 1, kE2);
        PHASE_BAR();
        // ph3: O mh0; RD O mh1; stage O'.B -> b1.s2/s3 (b1.B last read ph2)
        MMQ(0, 0, a0, bA); MMQ(0, 1, a0, bB);
        RD_AH(1, 1, a1);
        STAGE(pB, 0, 1, 2, kO2); STAGE(pB, 1, 1, 3, kO2);
        PHASE_BAR();
        // ph4: O mh1; guard b0=E' landed (ledger 12: oldest 8 = E'; last iter
        //      ph3 staged nothing -> drain all); RD E' mh0; stage O'.A -> b1
        MMQ(1, 0, a1, bA); MMQ(1, 1, a1, bB);
        if (i == GITERS - 1) { VMCNT0(); } else { VMCNT4(); }
        RD_AH(0, 0, a0); RD_BH(0, 0, bA); RD_BH(0, 1, bB);
        STAGE(pA, 0, 1, 0, kO2); STAGE(pA, 1, 1, 1, kO2);
        PHASE_BAR();
    }

    // tail: K-tile 68 in b0; mh0 frags preloaded at iter-33 ph4 (vmcnt(0) there)
    MMQ(0, 0, a0, bA); MMQ(0, 1, a0, bB);
    RD_AH(0, 1, a1);
    MMQ(1, 0, a1, bA); MMQ(1, 1, a1, bB);

    // epilogue: C/D layout col = lane&15, row = (lane>>4)*4 + reg
    const int crow0 = bm * 256 + wr * 128 + ((lane >> 4) << 2);
    const int ccol0 = bn * 256 + wc * 64 + (lane & 15);
#pragma unroll
    for (int m = 0; m < 8; ++m)
#pragma unroll
        for (int n = 0; n < 4; ++n)
#pragma unroll
            for (int rg = 0; rg < 4; ++rg)
                C[(size_t)(crow0 + m * 16 + rg) * DOUT + ccol0 + n * 16] = acc[m][n][rg];
}

// ---------------- launch ----------------

extern "C" void kernel_launch(void* const* d_in, const int* in_sizes, int n_in,
                              void* d_out, int out_size, void* d_ws, size_t ws_size,
                              hipStream_t stream) {
    const float* x         = (const float*)d_in[0];
    const float* W         = (const float*)d_in[1];
    const float* base_bias = (const float*)d_in[2];
    const float* lora_a    = (const float*)d_in[3];
    const float* lora_b    = (const float*)d_in[4];
    const float* bias_st   = (const float*)d_in[5];
    const int*   indices   = (const int*)d_in[6];
    float* out = (float*)d_out;

    u16* Abf  = (u16*)d_ws;                         // [T_TOK][K2] bf16
    u16* Bbf  = Abf + (size_t)T_TOK * K2;           // [DOUT][K2] bf16
    u16* Aabf = Bbf + (size_t)DOUT * K2;            // [256][DIN] bf16 lora_a

    pack_mats<<<6144, 256, 0, stream>>>(x, W, Abf, Bbf);
    pack_small<<<1536, 256, 0, stream>>>(lora_b, base_bias, bias_st, lora_a, Bbf, Aabf);
    zfill_kernel<<<256, 512, 0, stream>>>(Abf, Aabf, indices, Abf);
    gemm_kernel<<<512, 512, 0, stream>>>(Abf, Bbf, out);
    (void)in_sizes; (void)n_in; (void)out_size; (void)ws_size;
}